// Round 10
// baseline (5744.992 us; speedup 1.0000x reference)
//
#include <hip/hip_runtime.h>

// Problem constants
#define NN 50000
#define EE 600000
#define HH 128
#define KK 5
#define CC 60
#define NMODS 12
#define MAXPE 750080          // padded edge slots: E + 3N rounded up
#define SC_NB 49              // scan blocks: ceil(50000/1024)
#define MMGRID 391            // ceil(NN/128)

typedef _Float16 f16;
typedef __attribute__((ext_vector_type(8))) _Float16 f16x8;
typedef __attribute__((ext_vector_type(4))) _Float16 f16x4;
typedef __attribute__((ext_vector_type(16))) float f32x16;
typedef __attribute__((ext_vector_type(4))) int int4v;
typedef __attribute__((ext_vector_type(4))) float f32x4;

#define ZSL ((size_t)NN * 128)   // zcat slice stride (f16 elems)

#define GLOBAL_AS __attribute__((address_space(1)))
#define LDS_AS __attribute__((address_space(3)))

// ---------------- CSR build ----------------

__global__ void k_deg(const int* __restrict__ dst, int* __restrict__ deg) {
    int i = blockIdx.x * 256 + threadIdx.x;
    if (i < EE) atomicAdd(&deg[dst[i]], 1);
}

// scan of padded degrees, 1024 elems/block
__global__ __launch_bounds__(256) void k_scan1(const int* __restrict__ deg,
                                               int* __restrict__ rs, int* __restrict__ bsum) {
    __shared__ int sm[256];
    int t = threadIdx.x;
    int base = blockIdx.x * 1024 + t * 4;
    int d[4];
#pragma unroll
    for (int j = 0; j < 4; j++) {
        int i = base + j;
        d[j] = (i < NN) ? ((deg[i] + 3) & ~3) : 0;
    }
    int sum = d[0] + d[1] + d[2] + d[3];
    sm[t] = sum;
    __syncthreads();
    for (int off = 1; off < 256; off <<= 1) {
        int v = (t >= off) ? sm[t - off] : 0;
        __syncthreads();
        sm[t] += v;
        __syncthreads();
    }
    int excl = sm[t] - sum;
    int run = excl;
#pragma unroll
    for (int j = 0; j < 4; j++) {
        int i = base + j;
        if (i < NN) rs[i] = run;
        run += d[j];
    }
    if (t == 255) bsum[blockIdx.x] = sm[t];
}

__global__ __launch_bounds__(64) void k_scan2(const int* __restrict__ bsum, int* __restrict__ binc) {
    int l = threadIdx.x;
    int v = (l < SC_NB) ? bsum[l] : 0;
#pragma unroll
    for (int off = 1; off < 64; off <<= 1) {
        int tv = __shfl_up(v, off, 64);
        if (l >= off) v += tv;
    }
    binc[l] = v;  // inclusive
}

// scan finalize + degree norm (merged)
__global__ __launch_bounds__(256) void k_scan3(const int* __restrict__ binc, int* __restrict__ rs,
                                               const int* __restrict__ deg, float* __restrict__ norm) {
    int i = blockIdx.x * 256 + threadIdx.x;
    if (i < NN) {
        int b = i >> 10;
        if (b > 0) rs[i] += binc[b - 1];
        int d = deg[i];
        float fd = (float)(d < 1 ? 1 : d);
        norm[i] = 1.0f / sqrtf(fd);
    } else if (i == NN) {
        rs[NN] = binc[SC_NB - 1];
    }
}

// fill CSR: src ids, fused weights, and edge features permuted into CSR order
__global__ void k_fill(const int* __restrict__ src, const int* __restrict__ dst,
                       const int* __restrict__ rs, const float* __restrict__ norm,
                       int* __restrict__ cursor,
                       int* __restrict__ csrc, float* __restrict__ ew, float* __restrict__ efp,
                       const float* __restrict__ ef) {
    int i = blockIdx.x * 256 + threadIdx.x;
    if (i >= EE) return;
    int d = dst[i];
    int slot = atomicAdd(&cursor[d], 1);
    int p = rs[d] + slot;
    int s = src[i];
    csrc[p] = s;
    ew[p] = norm[s];
    ((float4*)efp)[p] = ((const float4*)ef)[i];
}

// ---------------- weight convert (f32 -> f16, transposed to [col][k]) ----------------

__global__ void k_cvtw(const float* __restrict__ conv_w, const float* __restrict__ ff_w,
                       const float* __restrict__ pose_w1,
                       f16* __restrict__ wc, f16* __restrict__ wf, f16* __restrict__ wp) {
    int i = blockIdx.x * 256 + threadIdx.x;
    const int NCW = 24 * 128 * 768;
    const int NFW = 12 * 128 * 128;
    const int NPW = 128 * 128;
    if (i < NCW) {
        int mat = i / (128 * 768); int rem = i - mat * (128 * 768);
        int col = rem / 768; int k = rem - col * 768;
        wc[i] = (f16)conv_w[(size_t)mat * 768 * 128 + (size_t)k * 128 + col];
    } else if (i < NCW + NFW) {
        int j = i - NCW;
        int mat = j / (128 * 128); int rem = j - mat * (128 * 128);
        int col = rem / 128; int k = rem - col * 128;
        wf[j] = (f16)ff_w[(size_t)mat * 128 * 128 + k * 128 + col];
    } else if (i < NCW + NFW + NPW) {
        int j = i - NCW - NFW;
        int col = j / 128; int k = j - col * 128;
        wp[j] = (f16)pose_w1[k * 128 + col];
    }
}

// ---------------- h0 = nf@in_w + in_b + pe@pos_w + pos_b + agg_e ----------------
// efp holds CSR-ordered edge features (zero in pad slots) -> sequential stream.

__global__ __launch_bounds__(128) void k_h0(
    const float* __restrict__ nf, const float* __restrict__ pe, const float* __restrict__ efp,
    const int* __restrict__ rs, const int* __restrict__ deg,
    const float* __restrict__ in_w, const float* __restrict__ in_b,
    const float* __restrict__ pos_w, const float* __restrict__ pos_b,
    const float* __restrict__ edge_w, const float* __restrict__ edge_b,
    float* __restrict__ h, f16* __restrict__ zc) {
    int n = blockIdx.x;
    int f = threadIdx.x;
    float v = in_b[f] + pos_b[f];
    v += nf[n * 2 + 0] * in_w[f] + nf[n * 2 + 1] * in_w[HH + f];
#pragma unroll
    for (int k = 0; k < KK; k++) v += pe[n * KK + k] * pos_w[k * HH + f];
    float e0 = edge_w[f], e1 = edge_w[HH + f], e2 = edge_w[2 * HH + f], e3 = edge_w[3 * HH + f];
    int s = rs[n], e = rs[n + 1];
    v += (float)deg[n] * edge_b[f];
    for (int i = s; i < e; i++) {
        float4 x = ((const float4*)efp)[i];   // zero in pad slots
        v += x.x * e0 + x.y * e1 + x.z * e2 + x.w * e3;
    }
    h[(size_t)n * HH + f] = v;
    zc[(size_t)n * 128 + f] = (f16)v;
}

// ---------------- propagation (fp16 dense [N][128] slices, f32 accumulate) ----------------
// 256 thr = 16 nodes x 16 lanes; lane covers 8 f16 cols. 8 edges in flight.
// BNF=1 (s=1 hop1): gather table is pre-BN yh; apply relu(v*sc+sh) in-flight and
// also materialize slice0 = bn(yh) for the conv GEMM (absorbs bnapply).

template <int BNF>
__global__ __launch_bounds__(256) void k_prop16(
    const f16* __restrict__ zin, f16* __restrict__ zout,
    const float* __restrict__ norm, const int* __restrict__ rs,
    const int* __restrict__ csrc, const float* __restrict__ ew,
    const float* __restrict__ sc, const float* __restrict__ sh,
    f16* __restrict__ zc0) {
    int tid = threadIdx.x;
    int n = blockIdx.x * 16 + (tid >> 4);
    int c = (tid & 15) * 8;
    float af[8], bf[8];
    if (BNF) {
#pragma unroll
        for (int j = 0; j < 8; j++) { af[j] = sc[c + j]; bf[j] = sh[c + j]; }
        // own-row: slice0[n] = relu(bn(yh[n]))
        f16x8 vo = *(const f16x8*)(zin + (size_t)n * 128 + c);
        f16x8 o0;
#pragma unroll
        for (int j = 0; j < 8; j++) o0[j] = (f16)fmaxf((float)vo[j] * af[j] + bf[j], 0.f);
        *(f16x8*)(zc0 + (size_t)n * 128 + c) = o0;
    }
    int s = rs[n], e = rs[n + 1];
    const f16* zp = zin + c;
    float acc[8] = {0.f, 0.f, 0.f, 0.f, 0.f, 0.f, 0.f, 0.f};
    auto term = [&](const f16x8& v, int j) -> float {
        float x = (float)v[j];
        if (BNF) x = fmaxf(x * af[j] + bf[j], 0.f);
        return x;
    };
    int i = s;
    for (; i + 8 <= e; i += 8) {
        int4v ia = __builtin_nontemporal_load((const int4v*)(csrc + i));
        int4v ib = __builtin_nontemporal_load((const int4v*)(csrc + i + 4));
        f32x4 wa = __builtin_nontemporal_load((const f32x4*)(ew + i));
        f32x4 wb = __builtin_nontemporal_load((const f32x4*)(ew + i + 4));
        f16x8 v0 = *(const f16x8*)(zp + (size_t)ia.x * 128);
        f16x8 v1 = *(const f16x8*)(zp + (size_t)ia.y * 128);
        f16x8 v2 = *(const f16x8*)(zp + (size_t)ia.z * 128);
        f16x8 v3 = *(const f16x8*)(zp + (size_t)ia.w * 128);
        f16x8 v4 = *(const f16x8*)(zp + (size_t)ib.x * 128);
        f16x8 v5 = *(const f16x8*)(zp + (size_t)ib.y * 128);
        f16x8 v6 = *(const f16x8*)(zp + (size_t)ib.z * 128);
        f16x8 v7 = *(const f16x8*)(zp + (size_t)ib.w * 128);
#pragma unroll
        for (int j = 0; j < 8; j++) {
            acc[j] += term(v0, j) * wa.x + term(v1, j) * wa.y +
                      term(v2, j) * wa.z + term(v3, j) * wa.w;
            acc[j] += term(v4, j) * wb.x + term(v5, j) * wb.y +
                      term(v6, j) * wb.z + term(v7, j) * wb.w;
        }
    }
    if (i < e) {
        int4v ia = __builtin_nontemporal_load((const int4v*)(csrc + i));
        f32x4 wa = __builtin_nontemporal_load((const f32x4*)(ew + i));
        f16x8 v0 = *(const f16x8*)(zp + (size_t)ia.x * 128);
        f16x8 v1 = *(const f16x8*)(zp + (size_t)ia.y * 128);
        f16x8 v2 = *(const f16x8*)(zp + (size_t)ia.z * 128);
        f16x8 v3 = *(const f16x8*)(zp + (size_t)ia.w * 128);
#pragma unroll
        for (int j = 0; j < 8; j++)
            acc[j] += term(v0, j) * wa.x + term(v1, j) * wa.y +
                      term(v2, j) * wa.z + term(v3, j) * wa.w;
    }
    // NOTE: pad slots have ew=0; with BNF, term() of garbage-free zero rows is
    // relu(0*a+b)=max(b,0) but multiplied by w=0 -> contributes 0. Safe.
    float nw = norm[n];
    f16x8 o;
#pragma unroll
    for (int j = 0; j < 8; j++) o[j] = (f16)(acc[j] * nw);
    *(f16x8*)(zout + (size_t)n * 128 + c) = o;
}

// ---------------- MFMA GEMM: Y[128 x 128] per block ----------------
// STATS: fused BN stats + last-block finalize -> sc/sh (no separate bnfin kernel).

template <int KT, int BIAS, int RESID, int RELU, int WRZ, int STATS, int YHF>
__global__ __launch_bounds__(256) void k_mm(
    const f16* __restrict__ A, const f16* __restrict__ Wt,
    const float* __restrict__ bias, const float* __restrict__ Rsd,
    float* __restrict__ Y, f16* __restrict__ Yh,
    f16* __restrict__ Zout, float* __restrict__ part,
    const float* __restrict__ bng, const float* __restrict__ bnb,
    float* __restrict__ sc, float* __restrict__ sh, int* __restrict__ cnt) {
    __shared__ char smem[65536];
    char* As = smem;
    char* Bs = smem + 32768;
    int tid = threadIdx.x;
    int lane = tid & 63;
    int w = tid >> 6, wm = w >> 1, wn = w & 1;
    int n0 = blockIdx.x * 128;
    f32x16 acc[2][2] = {};
    for (int k0 = 0; k0 < KT; k0 += 128) {
        __syncthreads();  // LDS reuse guard
        const f16* Asl = A + (size_t)(k0 >> 7) * ZSL;
#pragma unroll
        for (int i = 0; i < 8; i++) {
            int p = (i * 256 + tid) * 16;
            int o = p ^ (((p >> 8) & 15) << 4);   // inverse of read swizzle
            int r = o >> 8, ce = (o & 255) >> 1;
            int row = n0 + r; if (row >= NN) row = 0;  // clamp tail (stores guarded)
            const f16* ga = Asl + (size_t)row * 128 + ce;
            char* lba = As + i * 4096 + w * 1024;
            __builtin_amdgcn_global_load_lds((const GLOBAL_AS void*)ga, (LDS_AS void*)lba, 16, 0, 0);
            const f16* gb = Wt + (size_t)r * KT + k0 + ce;
            char* lbb = Bs + i * 4096 + w * 1024;
            __builtin_amdgcn_global_load_lds((const GLOBAL_AS void*)gb, (LDS_AS void*)lbb, 16, 0, 0);
        }
        asm volatile("s_waitcnt vmcnt(0)" ::: "memory");
        __syncthreads();
#pragma unroll
        for (int s = 0; s < 8; s++) {
            int koff = s * 32 + (lane >> 5) * 16;  // byte offset within 256B row
            f16x8 a[2], b[2];
#pragma unroll
            for (int m = 0; m < 2; m++) {
                int rl = wm * 64 + m * 32 + (lane & 31);
                int oa = (rl * 256 + koff) ^ ((rl & 15) << 4);
                a[m] = *(const f16x8*)(As + oa);
                int cl = wn * 64 + m * 32 + (lane & 31);
                int ob = (cl * 256 + koff) ^ ((cl & 15) << 4);
                b[m] = *(const f16x8*)(Bs + ob);
            }
#pragma unroll
            for (int m = 0; m < 2; m++)
#pragma unroll
                for (int nb = 0; nb < 2; nb++)
                    acc[m][nb] = __builtin_amdgcn_mfma_f32_32x32x16_f16(a[m], b[nb], acc[m][nb], 0, 0, 0);
        }
    }
    // epilogue: C/D layout col=lane&31, row=(reg&3)+8*(reg>>2)+4*(lane>>5)
    float ssum[2] = {0.f, 0.f}, sqq[2] = {0.f, 0.f};
#pragma unroll
    for (int m = 0; m < 2; m++) {
        int rb = n0 + wm * 64 + m * 32 + 4 * (lane >> 5);
#pragma unroll
        for (int nb = 0; nb < 2; nb++) {
            int col = wn * 64 + nb * 32 + (lane & 31);
            float bv = 0.f;
            if (BIAS) bv = bias[col];
#pragma unroll
            for (int r = 0; r < 16; r++) {
                int row = rb + (r & 3) + 8 * (r >> 2);
                if (row >= NN) continue;
                float v = acc[m][nb][r] + bv;
                if (RESID) v += Rsd[(size_t)row * HH + col];
                if (RELU) v = fmaxf(v, 0.f);
                if (STATS) { ssum[nb] += v; sqq[nb] += v * v; }
                if (YHF) Yh[(size_t)row * HH + col] = (f16)v;
                else Y[(size_t)row * HH + col] = v;
                if (WRZ) Zout[(size_t)row * 128 + col] = (f16)v;
            }
        }
    }
    if (STATS) {
        __syncthreads();               // all LDS frag reads done; reuse smem
        float* red = (float*)smem;     // [4 slots][256]
        int slot = wm * 2 + (lane >> 5);
        int colb = wn * 64 + (lane & 31);
        red[slot * 256 + colb] = ssum[0];
        red[slot * 256 + colb + 32] = ssum[1];
        red[slot * 256 + 128 + colb] = sqq[0];
        red[slot * 256 + 128 + colb + 32] = sqq[1];
        __syncthreads();
        float t = red[tid] + red[256 + tid] + red[512 + tid] + red[768 + tid];
        part[blockIdx.x * 256 + tid] = t;
        // last-block finalize (canonical pattern): part visible -> counter -> reduce
        __threadfence();
        __syncthreads();
        __shared__ int lastFlag;
        if (tid == 0) {
            int old = __hip_atomic_fetch_add(cnt, 1, __ATOMIC_ACQ_REL, __HIP_MEMORY_SCOPE_AGENT);
            lastFlag = (old == MMGRID - 1) ? 1 : 0;
        }
        __syncthreads();
        if (lastFlag) {
            if (tid < 128) {
                int f = tid;
                float s = 0.f, q = 0.f;
                for (int bi = 0; bi < MMGRID; bi++) {
                    s += part[bi * 256 + f];
                    q += part[bi * 256 + 128 + f];
                }
                float mean = s / (float)NN;
                float var = q / (float)NN - mean * mean;
                float scale = bng[f] / sqrtf(var + 1e-5f);
                sc[f] = scale;
                sh[f] = bnb[f] - mean * scale;
            }
            if (tid == 0) *cnt = 0;   // self-reset for next use (visible at kernel end)
        }
    }
}

// bnapply: reads f16 pre-BN y, writes f16 normalized+relu to zcat slice0 (s=1 only, feeds FF).

__global__ __launch_bounds__(256) void k_bnapply(const f16* __restrict__ Yh,
                                                 const float* __restrict__ sc, const float* __restrict__ sh,
                                                 f16* __restrict__ zc) {
    int idx = blockIdx.x * 256 + threadIdx.x;  // f16x8 index
    if (idx >= NN * 16) return;
    f16x8 v = ((const f16x8*)Yh)[idx];
    int c = (idx & 15) * 8;
    f16x8 o;
#pragma unroll
    for (int j = 0; j < 8; j++) {
        float a = sc[c + j], b = sh[c + j];
        o[j] = (f16)fmaxf((float)v[j] * a + b, 0.f);
    }
    ((f16x8*)zc)[idx] = o;
}

// ---------------- heads ----------------

__global__ __launch_bounds__(128) void k_pose2(const float* __restrict__ T,
                                               const float* __restrict__ W2, const float* __restrict__ b2,
                                               float* __restrict__ out) {
    int tid = threadIdx.x;
    int n = blockIdx.x * 4 + (tid >> 5);
    int c = tid & 31;
    float4 tv = ((const float4*)T)[(size_t)n * 32 + c];
    float p0 = 0.f, p1 = 0.f, p2 = 0.f;
#pragma unroll
    for (int i = 0; i < 4; i++) {
        float t = (i == 0) ? tv.x : (i == 1) ? tv.y : (i == 2) ? tv.z : tv.w;
        int k = c * 4 + i;
        p0 += t * W2[k * 3 + 0];
        p1 += t * W2[k * 3 + 1];
        p2 += t * W2[k * 3 + 2];
    }
#pragma unroll
    for (int off = 16; off > 0; off >>= 1) {
        p0 += __shfl_down(p0, off, 32);
        p1 += __shfl_down(p1, off, 32);
        p2 += __shfl_down(p2, off, 32);
    }
    if (c == 0) {
        out[(size_t)n * 3 + 0] = p0 + b2[0];
        out[(size_t)n * 3 + 1] = p1 + b2[1];
        out[(size_t)n * 3 + 2] = p2 + b2[2];
    }
}

__global__ __launch_bounds__(256) void k_meanpart(const float* __restrict__ Y, float* __restrict__ part) {
    int tid = threadIdx.x;
    float s = 0.f;
    for (int n = blockIdx.x * 2 + (tid >> 7); n < NN; n += 512) {
        s += Y[(size_t)n * HH + (tid & 127)];
    }
    __shared__ float sh[256];
    sh[tid] = s;
    __syncthreads();
    if (tid < 128) part[blockIdx.x * 128 + tid] = sh[tid] + sh[tid + 128];
}

__global__ __launch_bounds__(128) void k_labels(const float* __restrict__ part,
                                                const float* __restrict__ w1, const float* __restrict__ b1,
                                                const float* __restrict__ w2, const float* __restrict__ b2,
                                                float* __restrict__ out) {
    __shared__ float ym[128];
    __shared__ float t2[128];
    int f = threadIdx.x;
    float s = 0.f;
    for (int bi = 0; bi < 256; bi++) s += part[bi * 128 + f];
    ym[f] = s / (float)NN;
    __syncthreads();
    float a = b1[f];
    for (int k = 0; k < 128; k++) a += ym[k] * w1[k * 128 + f];
    t2[f] = fmaxf(a, 0.f);
    __syncthreads();
    if (f < CC) {
        float a2 = b2[f];
        for (int k = 0; k < 128; k++) a2 += t2[k] * w2[k * CC + f];
        out[(size_t)NN * 3 + f] = a2;
    }
}

// ---------------- launcher ----------------

static inline size_t align256(size_t x) { return (x + 255) & ~(size_t)255; }

extern "C" void kernel_launch(void* const* d_in, const int* in_sizes, int n_in,
                              void* d_out, int out_size, void* d_ws, size_t ws_size,
                              hipStream_t stream) {
    const float* nf = (const float*)d_in[0];
    const float* pe = (const float*)d_in[1];
    const float* ef = (const float*)d_in[2];
    const int* src = (const int*)d_in[3];
    const int* dst = (const int*)d_in[4];
    const float* in_w = (const float*)d_in[5];
    const float* in_b = (const float*)d_in[6];
    const float* pos_w = (const float*)d_in[7];
    const float* pos_b = (const float*)d_in[8];
    const float* edge_w = (const float*)d_in[9];
    const float* edge_b = (const float*)d_in[10];
    const float* conv_w = (const float*)d_in[11];
    // conv_b (d_in[12]) cancels exactly under training-mode BN -> skipped
    const float* bn_g = (const float*)d_in[13];
    const float* bn_b = (const float*)d_in[14];
    const float* ff_w = (const float*)d_in[15];
    const float* ff_b = (const float*)d_in[16];
    const float* pose_w1 = (const float*)d_in[17];
    const float* pose_b1 = (const float*)d_in[18];
    const float* pose_w2 = (const float*)d_in[19];
    const float* pose_b2 = (const float*)d_in[20];
    const float* lab_w1 = (const float*)d_in[21];
    const float* lab_b1 = (const float*)d_in[22];
    const float* lab_w2 = (const float*)d_in[23];
    const float* lab_b2 = (const float*)d_in[24];
    float* out = (float*)d_out;

    char* wsp = (char*)d_ws;
    size_t off = 0;
    auto alloc = [&](size_t bytes) -> void* {
        void* p = wsp + off;
        off += align256(bytes);
        return p;
    };
    float* norm = (float*)alloc((size_t)NN * 4);
    int* deg = (int*)alloc((size_t)NN * 4);
    int* rs = (int*)alloc((size_t)(NN + 1) * 4);
    int* cursor = (int*)alloc((size_t)NN * 4);
    int* csrc = (int*)alloc((size_t)MAXPE * 4);
    float* ew = (float*)alloc((size_t)MAXPE * 4);
    float* efp = (float*)alloc((size_t)MAXPE * 16);
    int* bsum = (int*)alloc(64 * 4);
    int* binc = (int*)alloc(64 * 4);
    int* cnt = (int*)alloc(256);
    float* hin = (float*)alloc((size_t)NN * HH * 4);
    float* ybuf = (float*)alloc((size_t)NN * HH * 4);   // f32 (pose head t)
    f16* yh = (f16*)alloc((size_t)NN * HH * 2);          // f16 pre-BN conv output
    f16* zcat = (f16*)alloc((size_t)6 * ZSL * 2);
    f16* wc = (f16*)alloc((size_t)24 * 128 * 768 * 2);
    f16* wf = (f16*)alloc((size_t)12 * 128 * 128 * 2);
    f16* wp = (f16*)alloc((size_t)128 * 128 * 2);
    float* part = (float*)alloc((size_t)MMGRID * 256 * 4);
    float* mpart = (float*)alloc(256 * 128 * 4);
    float* bnsc = (float*)alloc(128 * 4);
    float* bnsh = (float*)alloc(128 * 4);
    (void)ws_size; (void)in_sizes; (void)n_in; (void)out_size;

    // CSR build (padded-to-4 edge lists, fused edge weights, permuted edge features)
    hipMemsetAsync(deg, 0, (size_t)NN * 4, stream);
    hipMemsetAsync(cursor, 0, (size_t)NN * 4, stream);
    hipMemsetAsync(csrc, 0, (size_t)MAXPE * 4, stream);
    hipMemsetAsync(ew, 0, (size_t)MAXPE * 4, stream);
    hipMemsetAsync(efp, 0, (size_t)MAXPE * 16, stream);
    hipMemsetAsync(cnt, 0, 4, stream);
    int egrid = (EE + 255) / 256;
    k_deg<<<egrid, 256, 0, stream>>>(dst, deg);
    k_scan1<<<SC_NB, 256, 0, stream>>>(deg, rs, bsum);
    k_scan2<<<1, 64, 0, stream>>>(bsum, binc);
    k_scan3<<<(NN + 256) / 256, 256, 0, stream>>>(binc, rs, deg, norm);
    k_fill<<<egrid, 256, 0, stream>>>(src, dst, rs, norm, cursor, csrc, ew, efp, ef);

    // weight conversion
    const int NCVT = 24 * 128 * 768 + 12 * 128 * 128 + 128 * 128;
    k_cvtw<<<(NCVT + 255) / 256, 256, 0, stream>>>(conv_w, ff_w, pose_w1, wc, wf, wp);

    // h0
    k_h0<<<NN, 128, 0, stream>>>(nf, pe, efp, rs, deg, in_w, in_b, pos_w, pos_b,
                                 edge_w, edge_b, hin, zcat);

    const int pgrid = (NN + 15) / 16;        // 3125
    const int agrid = (NN * 16 + 255) / 256; // 3125

    for (int m = 0; m < NMODS; m++) {
        // ---- s=0 tagconv: input = zcat slice0 (h0 or previous ff)
        {
            const f16* Wb = wc + (size_t)(m * 2 + 0) * 128 * 768;
            for (int k = 1; k <= KK; k++) {
                k_prop16<0><<<pgrid, 256, 0, stream>>>(zcat + (size_t)(k - 1) * ZSL,
                                                       zcat + (size_t)k * ZSL,
                                                       norm, rs, csrc, ew,
                                                       nullptr, nullptr, nullptr);
            }
            k_mm<768, 0, 0, 0, 0, 1, 1><<<MMGRID, 256, 0, stream>>>(
                zcat, Wb, nullptr, nullptr, nullptr, yh, nullptr, part,
                bn_g + (size_t)(m * 2 + 0) * HH, bn_b + (size_t)(m * 2 + 0) * HH,
                bnsc, bnsh, cnt);
        }
        // ---- s=1 tagconv: hop1 gathers bn(yh) on the fly + writes slice0
        {
            const f16* Wb = wc + (size_t)(m * 2 + 1) * 128 * 768;
            k_prop16<1><<<pgrid, 256, 0, stream>>>(yh, zcat + ZSL,
                                                   norm, rs, csrc, ew,
                                                   bnsc, bnsh, zcat);
            for (int k = 2; k <= KK; k++) {
                k_prop16<0><<<pgrid, 256, 0, stream>>>(zcat + (size_t)(k - 1) * ZSL,
                                                       zcat + (size_t)k * ZSL,
                                                       norm, rs, csrc, ew,
                                                       nullptr, nullptr, nullptr);
            }
            k_mm<768, 0, 0, 0, 0, 1, 1><<<MMGRID, 256, 0, stream>>>(
                zcat, Wb, nullptr, nullptr, nullptr, yh, nullptr, part,
                bn_g + (size_t)(m * 2 + 1) * HH, bn_b + (size_t)(m * 2 + 1) * HH,
                bnsc, bnsh, cnt);
        }
        // slice0 = bn(yh_s1) for the FF GEMM
        k_bnapply<<<agrid, 256, 0, stream>>>(yh, bnsc, bnsh, zcat);
        // ff + residual: hin = f16(zcat0)@ff_w + ff_b + hin ; also writes zcat slice0
        k_mm<128, 1, 1, 0, 1, 0, 0><<<MMGRID, 256, 0, stream>>>(
            zcat, wf + (size_t)m * 128 * 128, ff_b + (size_t)m * HH, hin,
            hin, nullptr, zcat, nullptr, nullptr, nullptr, nullptr, nullptr, nullptr);
    }

    // pose head: t = relu(h@W1+b1) -> ybuf, then pose = t@W2+b2
    k_mm<128, 1, 0, 1, 0, 0, 0><<<MMGRID, 256, 0, stream>>>(
        zcat, wp, pose_b1, nullptr, ybuf, nullptr, nullptr, nullptr,
        nullptr, nullptr, nullptr, nullptr, nullptr);
    k_pose2<<<NN / 4, 128, 0, stream>>>(ybuf, pose_w2, pose_b2, out);

    // labels head
    k_meanpart<<<256, 256, 0, stream>>>(hin, mpart);
    k_labels<<<1, 128, 0, stream>>>(mpart, lab_w1, lab_b1, lab_w2, lab_b2, out);
}

// Round 11
// 4697.553 us; speedup vs baseline: 1.2230x; 1.2230x over previous
//
#include <hip/hip_runtime.h>

// Problem constants
#define NN 50000
#define EE 600000
#define HH 128
#define KK 5
#define CC 60
#define NMODS 12
#define MAXPE 750080          // padded edge slots: E + 3N rounded up
#define SC_NB 49              // scan blocks: ceil(50000/1024)
#define MMGRID 391            // ceil(NN/128)

typedef _Float16 f16;
typedef __attribute__((ext_vector_type(8))) _Float16 f16x8;
typedef __attribute__((ext_vector_type(4))) _Float16 f16x4;
typedef __attribute__((ext_vector_type(16))) float f32x16;
typedef __attribute__((ext_vector_type(4))) int int4v;
typedef __attribute__((ext_vector_type(4))) float f32x4;

#define ZSL ((size_t)NN * 128)   // zcat slice stride (f16 elems)

#define GLOBAL_AS __attribute__((address_space(1)))
#define LDS_AS __attribute__((address_space(3)))

// ---------------- CSR build ----------------

__global__ void k_deg(const int* __restrict__ dst, int* __restrict__ deg) {
    int i = blockIdx.x * 256 + threadIdx.x;
    if (i < EE) atomicAdd(&deg[dst[i]], 1);
}

// scan of padded degrees, 1024 elems/block
__global__ __launch_bounds__(256) void k_scan1(const int* __restrict__ deg,
                                               int* __restrict__ rs, int* __restrict__ bsum) {
    __shared__ int sm[256];
    int t = threadIdx.x;
    int base = blockIdx.x * 1024 + t * 4;
    int d[4];
#pragma unroll
    for (int j = 0; j < 4; j++) {
        int i = base + j;
        d[j] = (i < NN) ? ((deg[i] + 3) & ~3) : 0;
    }
    int sum = d[0] + d[1] + d[2] + d[3];
    sm[t] = sum;
    __syncthreads();
    for (int off = 1; off < 256; off <<= 1) {
        int v = (t >= off) ? sm[t - off] : 0;
        __syncthreads();
        sm[t] += v;
        __syncthreads();
    }
    int excl = sm[t] - sum;
    int run = excl;
#pragma unroll
    for (int j = 0; j < 4; j++) {
        int i = base + j;
        if (i < NN) rs[i] = run;
        run += d[j];
    }
    if (t == 255) bsum[blockIdx.x] = sm[t];
}

__global__ __launch_bounds__(64) void k_scan2(const int* __restrict__ bsum, int* __restrict__ binc) {
    int l = threadIdx.x;
    int v = (l < SC_NB) ? bsum[l] : 0;
#pragma unroll
    for (int off = 1; off < 64; off <<= 1) {
        int tv = __shfl_up(v, off, 64);
        if (l >= off) v += tv;
    }
    binc[l] = v;  // inclusive
}

// scan finalize + degree norm (merged)
__global__ __launch_bounds__(256) void k_scan3(const int* __restrict__ binc, int* __restrict__ rs,
                                               const int* __restrict__ deg, float* __restrict__ norm) {
    int i = blockIdx.x * 256 + threadIdx.x;
    if (i < NN) {
        int b = i >> 10;
        if (b > 0) rs[i] += binc[b - 1];
        int d = deg[i];
        float fd = (float)(d < 1 ? 1 : d);
        norm[i] = 1.0f / sqrtf(fd);
    } else if (i == NN) {
        rs[NN] = binc[SC_NB - 1];
    }
}

// fill CSR: src ids, fused weights, and edge features permuted into CSR order
__global__ void k_fill(const int* __restrict__ src, const int* __restrict__ dst,
                       const int* __restrict__ rs, const float* __restrict__ norm,
                       int* __restrict__ cursor,
                       int* __restrict__ csrc, float* __restrict__ ew, float* __restrict__ efp,
                       const float* __restrict__ ef) {
    int i = blockIdx.x * 256 + threadIdx.x;
    if (i >= EE) return;
    int d = dst[i];
    int slot = atomicAdd(&cursor[d], 1);
    int p = rs[d] + slot;
    int s = src[i];
    csrc[p] = s;
    ew[p] = norm[s];
    ((float4*)efp)[p] = ((const float4*)ef)[i];
}

// ---------------- weight convert (f32 -> f16, transposed to [col][k]) ----------------

__global__ void k_cvtw(const float* __restrict__ conv_w, const float* __restrict__ ff_w,
                       const float* __restrict__ pose_w1,
                       f16* __restrict__ wc, f16* __restrict__ wf, f16* __restrict__ wp) {
    int i = blockIdx.x * 256 + threadIdx.x;
    const int NCW = 24 * 128 * 768;
    const int NFW = 12 * 128 * 128;
    const int NPW = 128 * 128;
    if (i < NCW) {
        int mat = i / (128 * 768); int rem = i - mat * (128 * 768);
        int col = rem / 768; int k = rem - col * 768;
        wc[i] = (f16)conv_w[(size_t)mat * 768 * 128 + (size_t)k * 128 + col];
    } else if (i < NCW + NFW) {
        int j = i - NCW;
        int mat = j / (128 * 128); int rem = j - mat * (128 * 128);
        int col = rem / 128; int k = rem - col * 128;
        wf[j] = (f16)ff_w[(size_t)mat * 128 * 128 + k * 128 + col];
    } else if (i < NCW + NFW + NPW) {
        int j = i - NCW - NFW;
        int col = j / 128; int k = j - col * 128;
        wp[j] = (f16)pose_w1[k * 128 + col];
    }
}

// ---------------- h0 = nf@in_w + in_b + pe@pos_w + pos_b + agg_e ----------------
// efp holds CSR-ordered edge features (zero in pad slots) -> sequential stream.

__global__ __launch_bounds__(128) void k_h0(
    const float* __restrict__ nf, const float* __restrict__ pe, const float* __restrict__ efp,
    const int* __restrict__ rs, const int* __restrict__ deg,
    const float* __restrict__ in_w, const float* __restrict__ in_b,
    const float* __restrict__ pos_w, const float* __restrict__ pos_b,
    const float* __restrict__ edge_w, const float* __restrict__ edge_b,
    float* __restrict__ h, f16* __restrict__ zc) {
    int n = blockIdx.x;
    int f = threadIdx.x;
    float v = in_b[f] + pos_b[f];
    v += nf[n * 2 + 0] * in_w[f] + nf[n * 2 + 1] * in_w[HH + f];
#pragma unroll
    for (int k = 0; k < KK; k++) v += pe[n * KK + k] * pos_w[k * HH + f];
    float e0 = edge_w[f], e1 = edge_w[HH + f], e2 = edge_w[2 * HH + f], e3 = edge_w[3 * HH + f];
    int s = rs[n], e = rs[n + 1];
    v += (float)deg[n] * edge_b[f];
    for (int i = s; i < e; i++) {
        float4 x = ((const float4*)efp)[i];   // zero in pad slots
        v += x.x * e0 + x.y * e1 + x.z * e2 + x.w * e3;
    }
    h[(size_t)n * HH + f] = v;
    zc[(size_t)n * 128 + f] = (f16)v;
}

// ---------------- propagation (fp16 dense [N][128] slices, f32 accumulate) ----------------
// 256 thr = 16 nodes x 16 lanes; lane covers 8 f16 cols. 8 edges in flight.
// BNF=1 (s=1 hop1): gather table is pre-BN yh; apply relu(v*sc+sh) in-flight and
// also materialize slice0 = bn(yh) for the conv GEMM (absorbs bnapply).

template <int BNF>
__global__ __launch_bounds__(256) void k_prop16(
    const f16* __restrict__ zin, f16* __restrict__ zout,
    const float* __restrict__ norm, const int* __restrict__ rs,
    const int* __restrict__ csrc, const float* __restrict__ ew,
    const float* __restrict__ sc, const float* __restrict__ sh,
    f16* __restrict__ zc0) {
    int tid = threadIdx.x;
    int n = blockIdx.x * 16 + (tid >> 4);
    int c = (tid & 15) * 8;
    float af[8], bf[8];
    if (BNF) {
#pragma unroll
        for (int j = 0; j < 8; j++) { af[j] = sc[c + j]; bf[j] = sh[c + j]; }
        // own-row: slice0[n] = relu(bn(yh[n]))
        f16x8 vo = *(const f16x8*)(zin + (size_t)n * 128 + c);
        f16x8 o0;
#pragma unroll
        for (int j = 0; j < 8; j++) o0[j] = (f16)fmaxf((float)vo[j] * af[j] + bf[j], 0.f);
        *(f16x8*)(zc0 + (size_t)n * 128 + c) = o0;
    }
    int s = rs[n], e = rs[n + 1];
    const f16* zp = zin + c;
    float acc[8] = {0.f, 0.f, 0.f, 0.f, 0.f, 0.f, 0.f, 0.f};
    auto term = [&](const f16x8& v, int j) -> float {
        float x = (float)v[j];
        if (BNF) x = fmaxf(x * af[j] + bf[j], 0.f);
        return x;
    };
    int i = s;
    for (; i + 8 <= e; i += 8) {
        int4v ia = __builtin_nontemporal_load((const int4v*)(csrc + i));
        int4v ib = __builtin_nontemporal_load((const int4v*)(csrc + i + 4));
        f32x4 wa = __builtin_nontemporal_load((const f32x4*)(ew + i));
        f32x4 wb = __builtin_nontemporal_load((const f32x4*)(ew + i + 4));
        f16x8 v0 = *(const f16x8*)(zp + (size_t)ia.x * 128);
        f16x8 v1 = *(const f16x8*)(zp + (size_t)ia.y * 128);
        f16x8 v2 = *(const f16x8*)(zp + (size_t)ia.z * 128);
        f16x8 v3 = *(const f16x8*)(zp + (size_t)ia.w * 128);
        f16x8 v4 = *(const f16x8*)(zp + (size_t)ib.x * 128);
        f16x8 v5 = *(const f16x8*)(zp + (size_t)ib.y * 128);
        f16x8 v6 = *(const f16x8*)(zp + (size_t)ib.z * 128);
        f16x8 v7 = *(const f16x8*)(zp + (size_t)ib.w * 128);
#pragma unroll
        for (int j = 0; j < 8; j++) {
            acc[j] += term(v0, j) * wa.x + term(v1, j) * wa.y +
                      term(v2, j) * wa.z + term(v3, j) * wa.w;
            acc[j] += term(v4, j) * wb.x + term(v5, j) * wb.y +
                      term(v6, j) * wb.z + term(v7, j) * wb.w;
        }
    }
    if (i < e) {
        int4v ia = __builtin_nontemporal_load((const int4v*)(csrc + i));
        f32x4 wa = __builtin_nontemporal_load((const f32x4*)(ew + i));
        f16x8 v0 = *(const f16x8*)(zp + (size_t)ia.x * 128);
        f16x8 v1 = *(const f16x8*)(zp + (size_t)ia.y * 128);
        f16x8 v2 = *(const f16x8*)(zp + (size_t)ia.z * 128);
        f16x8 v3 = *(const f16x8*)(zp + (size_t)ia.w * 128);
#pragma unroll
        for (int j = 0; j < 8; j++)
            acc[j] += term(v0, j) * wa.x + term(v1, j) * wa.y +
                      term(v2, j) * wa.z + term(v3, j) * wa.w;
    }
    // pad slots have ew=0; with BNF, term() of zero rows is max(b,0) times w=0 -> 0. Safe.
    float nw = norm[n];
    f16x8 o;
#pragma unroll
    for (int j = 0; j < 8; j++) o[j] = (f16)(acc[j] * nw);
    *(f16x8*)(zout + (size_t)n * 128 + c) = o;
}

// ---------------- MFMA GEMM: Y[128 x 128] per block ----------------
// STATS: per-block per-column (sum, sumsq) partials -> part[block][256].
// (No in-kernel finalize: agent-scope fencing in the epilogue tripled GEMM time, r10.)

template <int KT, int BIAS, int RESID, int RELU, int WRZ, int STATS, int YHF>
__global__ __launch_bounds__(256) void k_mm(
    const f16* __restrict__ A, const f16* __restrict__ Wt,
    const float* __restrict__ bias, const float* __restrict__ Rsd,
    float* __restrict__ Y, f16* __restrict__ Yh,
    f16* __restrict__ Zout, float* __restrict__ part) {
    __shared__ char smem[65536];
    char* As = smem;
    char* Bs = smem + 32768;
    int tid = threadIdx.x;
    int lane = tid & 63;
    int w = tid >> 6, wm = w >> 1, wn = w & 1;
    int n0 = blockIdx.x * 128;
    f32x16 acc[2][2] = {};
    for (int k0 = 0; k0 < KT; k0 += 128) {
        __syncthreads();  // LDS reuse guard
        const f16* Asl = A + (size_t)(k0 >> 7) * ZSL;
#pragma unroll
        for (int i = 0; i < 8; i++) {
            int p = (i * 256 + tid) * 16;
            int o = p ^ (((p >> 8) & 15) << 4);   // inverse of read swizzle
            int r = o >> 8, ce = (o & 255) >> 1;
            int row = n0 + r; if (row >= NN) row = 0;  // clamp tail (stores guarded)
            const f16* ga = Asl + (size_t)row * 128 + ce;
            char* lba = As + i * 4096 + w * 1024;
            __builtin_amdgcn_global_load_lds((const GLOBAL_AS void*)ga, (LDS_AS void*)lba, 16, 0, 0);
            const f16* gb = Wt + (size_t)r * KT + k0 + ce;
            char* lbb = Bs + i * 4096 + w * 1024;
            __builtin_amdgcn_global_load_lds((const GLOBAL_AS void*)gb, (LDS_AS void*)lbb, 16, 0, 0);
        }
        asm volatile("s_waitcnt vmcnt(0)" ::: "memory");
        __syncthreads();
#pragma unroll
        for (int s = 0; s < 8; s++) {
            int koff = s * 32 + (lane >> 5) * 16;  // byte offset within 256B row
            f16x8 a[2], b[2];
#pragma unroll
            for (int m = 0; m < 2; m++) {
                int rl = wm * 64 + m * 32 + (lane & 31);
                int oa = (rl * 256 + koff) ^ ((rl & 15) << 4);
                a[m] = *(const f16x8*)(As + oa);
                int cl = wn * 64 + m * 32 + (lane & 31);
                int ob = (cl * 256 + koff) ^ ((cl & 15) << 4);
                b[m] = *(const f16x8*)(Bs + ob);
            }
#pragma unroll
            for (int m = 0; m < 2; m++)
#pragma unroll
                for (int nb = 0; nb < 2; nb++)
                    acc[m][nb] = __builtin_amdgcn_mfma_f32_32x32x16_f16(a[m], b[nb], acc[m][nb], 0, 0, 0);
        }
    }
    // epilogue: C/D layout col=lane&31, row=(reg&3)+8*(reg>>2)+4*(lane>>5)
    float ssum[2] = {0.f, 0.f}, sqq[2] = {0.f, 0.f};
#pragma unroll
    for (int m = 0; m < 2; m++) {
        int rb = n0 + wm * 64 + m * 32 + 4 * (lane >> 5);
#pragma unroll
        for (int nb = 0; nb < 2; nb++) {
            int col = wn * 64 + nb * 32 + (lane & 31);
            float bv = 0.f;
            if (BIAS) bv = bias[col];
#pragma unroll
            for (int r = 0; r < 16; r++) {
                int row = rb + (r & 3) + 8 * (r >> 2);
                if (row >= NN) continue;
                float v = acc[m][nb][r] + bv;
                if (RESID) v += Rsd[(size_t)row * HH + col];
                if (RELU) v = fmaxf(v, 0.f);
                if (STATS) { ssum[nb] += v; sqq[nb] += v * v; }
                if (YHF) Yh[(size_t)row * HH + col] = (f16)v;
                else Y[(size_t)row * HH + col] = v;
                if (WRZ) Zout[(size_t)row * 128 + col] = (f16)v;
            }
        }
    }
    if (STATS) {
        __syncthreads();               // all LDS frag reads done; reuse smem
        float* red = (float*)smem;     // [4 slots][256]
        int slot = wm * 2 + (lane >> 5);
        int colb = wn * 64 + (lane & 31);
        red[slot * 256 + colb] = ssum[0];
        red[slot * 256 + colb + 32] = ssum[1];
        red[slot * 256 + 128 + colb] = sqq[0];
        red[slot * 256 + 128 + colb + 32] = sqq[1];
        __syncthreads();
        float t = red[tid] + red[256 + tid] + red[512 + tid] + red[768 + tid];
        part[blockIdx.x * 256 + tid] = t;
    }
}

// ---------------- BatchNorm finalize (parallel reduce of MMGRID block partials) ----------------
// 1024 threads = 8 row-groups x 128 cols; ~49 partial rows per group, LDS tree.

__global__ __launch_bounds__(1024) void k_bnfin(const float* __restrict__ part,
                                                const float* __restrict__ g, const float* __restrict__ b,
                                                float* __restrict__ sc, float* __restrict__ sh) {
    __shared__ float rsm[8][128];
    __shared__ float rqm[8][128];
    int tid = threadIdx.x;
    int f = tid & 127, grp = tid >> 7;
    float s = 0.f, q = 0.f;
    for (int bi = grp; bi < MMGRID; bi += 8) {
        s += part[bi * 256 + f];
        q += part[bi * 256 + 128 + f];
    }
    rsm[grp][f] = s;
    rqm[grp][f] = q;
    __syncthreads();
    if (tid < 128) {
        float ss = 0.f, qq = 0.f;
#pragma unroll
        for (int gq = 0; gq < 8; gq++) { ss += rsm[gq][f]; qq += rqm[gq][f]; }
        float mean = ss / (float)NN;
        float var = qq / (float)NN - mean * mean;
        float scale = g[f] / sqrtf(var + 1e-5f);
        sc[f] = scale;
        sh[f] = b[f] - mean * scale;
    }
}

// bnapply: reads f16 pre-BN y, writes f16 normalized+relu to zcat slice0 (s=1 only, feeds FF).

__global__ __launch_bounds__(256) void k_bnapply(const f16* __restrict__ Yh,
                                                 const float* __restrict__ sc, const float* __restrict__ sh,
                                                 f16* __restrict__ zc) {
    int idx = blockIdx.x * 256 + threadIdx.x;  // f16x8 index
    if (idx >= NN * 16) return;
    f16x8 v = ((const f16x8*)Yh)[idx];
    int c = (idx & 15) * 8;
    f16x8 o;
#pragma unroll
    for (int j = 0; j < 8; j++) {
        float a = sc[c + j], b = sh[c + j];
        o[j] = (f16)fmaxf((float)v[j] * a + b, 0.f);
    }
    ((f16x8*)zc)[idx] = o;
}

// ---------------- heads ----------------

__global__ __launch_bounds__(128) void k_pose2(const float* __restrict__ T,
                                               const float* __restrict__ W2, const float* __restrict__ b2,
                                               float* __restrict__ out) {
    int tid = threadIdx.x;
    int n = blockIdx.x * 4 + (tid >> 5);
    int c = tid & 31;
    float4 tv = ((const float4*)T)[(size_t)n * 32 + c];
    float p0 = 0.f, p1 = 0.f, p2 = 0.f;
#pragma unroll
    for (int i = 0; i < 4; i++) {
        float t = (i == 0) ? tv.x : (i == 1) ? tv.y : (i == 2) ? tv.z : tv.w;
        int k = c * 4 + i;
        p0 += t * W2[k * 3 + 0];
        p1 += t * W2[k * 3 + 1];
        p2 += t * W2[k * 3 + 2];
    }
#pragma unroll
    for (int off = 16; off > 0; off >>= 1) {
        p0 += __shfl_down(p0, off, 32);
        p1 += __shfl_down(p1, off, 32);
        p2 += __shfl_down(p2, off, 32);
    }
    if (c == 0) {
        out[(size_t)n * 3 + 0] = p0 + b2[0];
        out[(size_t)n * 3 + 1] = p1 + b2[1];
        out[(size_t)n * 3 + 2] = p2 + b2[2];
    }
}

__global__ __launch_bounds__(256) void k_meanpart(const float* __restrict__ Y, float* __restrict__ part) {
    int tid = threadIdx.x;
    float s = 0.f;
    for (int n = blockIdx.x * 2 + (tid >> 7); n < NN; n += 512) {
        s += Y[(size_t)n * HH + (tid & 127)];
    }
    __shared__ float sh[256];
    sh[tid] = s;
    __syncthreads();
    if (tid < 128) part[blockIdx.x * 128 + tid] = sh[tid] + sh[tid + 128];
}

__global__ __launch_bounds__(128) void k_labels(const float* __restrict__ part,
                                                const float* __restrict__ w1, const float* __restrict__ b1,
                                                const float* __restrict__ w2, const float* __restrict__ b2,
                                                float* __restrict__ out) {
    __shared__ float ym[128];
    __shared__ float t2[128];
    int f = threadIdx.x;
    float s = 0.f;
    for (int bi = 0; bi < 256; bi++) s += part[bi * 128 + f];
    ym[f] = s / (float)NN;
    __syncthreads();
    float a = b1[f];
    for (int k = 0; k < 128; k++) a += ym[k] * w1[k * 128 + f];
    t2[f] = fmaxf(a, 0.f);
    __syncthreads();
    if (f < CC) {
        float a2 = b2[f];
        for (int k = 0; k < 128; k++) a2 += t2[k] * w2[k * CC + f];
        out[(size_t)NN * 3 + f] = a2;
    }
}

// ---------------- launcher ----------------

static inline size_t align256(size_t x) { return (x + 255) & ~(size_t)255; }

extern "C" void kernel_launch(void* const* d_in, const int* in_sizes, int n_in,
                              void* d_out, int out_size, void* d_ws, size_t ws_size,
                              hipStream_t stream) {
    const float* nf = (const float*)d_in[0];
    const float* pe = (const float*)d_in[1];
    const float* ef = (const float*)d_in[2];
    const int* src = (const int*)d_in[3];
    const int* dst = (const int*)d_in[4];
    const float* in_w = (const float*)d_in[5];
    const float* in_b = (const float*)d_in[6];
    const float* pos_w = (const float*)d_in[7];
    const float* pos_b = (const float*)d_in[8];
    const float* edge_w = (const float*)d_in[9];
    const float* edge_b = (const float*)d_in[10];
    const float* conv_w = (const float*)d_in[11];
    // conv_b (d_in[12]) cancels exactly under training-mode BN -> skipped
    const float* bn_g = (const float*)d_in[13];
    const float* bn_b = (const float*)d_in[14];
    const float* ff_w = (const float*)d_in[15];
    const float* ff_b = (const float*)d_in[16];
    const float* pose_w1 = (const float*)d_in[17];
    const float* pose_b1 = (const float*)d_in[18];
    const float* pose_w2 = (const float*)d_in[19];
    const float* pose_b2 = (const float*)d_in[20];
    const float* lab_w1 = (const float*)d_in[21];
    const float* lab_b1 = (const float*)d_in[22];
    const float* lab_w2 = (const float*)d_in[23];
    const float* lab_b2 = (const float*)d_in[24];
    float* out = (float*)d_out;

    char* wsp = (char*)d_ws;
    size_t off = 0;
    auto alloc = [&](size_t bytes) -> void* {
        void* p = wsp + off;
        off += align256(bytes);
        return p;
    };
    float* norm = (float*)alloc((size_t)NN * 4);
    int* deg = (int*)alloc((size_t)NN * 4);
    int* rs = (int*)alloc((size_t)(NN + 1) * 4);
    int* cursor = (int*)alloc((size_t)NN * 4);
    int* csrc = (int*)alloc((size_t)MAXPE * 4);
    float* ew = (float*)alloc((size_t)MAXPE * 4);
    float* efp = (float*)alloc((size_t)MAXPE * 16);
    int* bsum = (int*)alloc(64 * 4);
    int* binc = (int*)alloc(64 * 4);
    float* hin = (float*)alloc((size_t)NN * HH * 4);
    float* ybuf = (float*)alloc((size_t)NN * HH * 4);   // f32 (pose head t)
    f16* yh = (f16*)alloc((size_t)NN * HH * 2);          // f16 pre-BN conv output
    f16* zcat = (f16*)alloc((size_t)6 * ZSL * 2);
    f16* wc = (f16*)alloc((size_t)24 * 128 * 768 * 2);
    f16* wf = (f16*)alloc((size_t)12 * 128 * 128 * 2);
    f16* wp = (f16*)alloc((size_t)128 * 128 * 2);
    float* part = (float*)alloc((size_t)MMGRID * 256 * 4);
    float* mpart = (float*)alloc(256 * 128 * 4);
    float* bnsc = (float*)alloc(128 * 4);
    float* bnsh = (float*)alloc(128 * 4);
    (void)ws_size; (void)in_sizes; (void)n_in; (void)out_size;

    // CSR build (padded-to-4 edge lists, fused edge weights, permuted edge features)
    hipMemsetAsync(deg, 0, (size_t)NN * 4, stream);
    hipMemsetAsync(cursor, 0, (size_t)NN * 4, stream);
    hipMemsetAsync(csrc, 0, (size_t)MAXPE * 4, stream);
    hipMemsetAsync(ew, 0, (size_t)MAXPE * 4, stream);
    hipMemsetAsync(efp, 0, (size_t)MAXPE * 16, stream);
    int egrid = (EE + 255) / 256;
    k_deg<<<egrid, 256, 0, stream>>>(dst, deg);
    k_scan1<<<SC_NB, 256, 0, stream>>>(deg, rs, bsum);
    k_scan2<<<1, 64, 0, stream>>>(bsum, binc);
    k_scan3<<<(NN + 256) / 256, 256, 0, stream>>>(binc, rs, deg, norm);
    k_fill<<<egrid, 256, 0, stream>>>(src, dst, rs, norm, cursor, csrc, ew, efp, ef);

    // weight conversion
    const int NCVT = 24 * 128 * 768 + 12 * 128 * 128 + 128 * 128;
    k_cvtw<<<(NCVT + 255) / 256, 256, 0, stream>>>(conv_w, ff_w, pose_w1, wc, wf, wp);

    // h0
    k_h0<<<NN, 128, 0, stream>>>(nf, pe, efp, rs, deg, in_w, in_b, pos_w, pos_b,
                                 edge_w, edge_b, hin, zcat);

    const int pgrid = (NN + 15) / 16;        // 3125
    const int agrid = (NN * 16 + 255) / 256; // 3125

    for (int m = 0; m < NMODS; m++) {
        // ---- s=0 tagconv: input = zcat slice0 (h0 or previous ff)
        {
            const f16* Wb = wc + (size_t)(m * 2 + 0) * 128 * 768;
            for (int k = 1; k <= KK; k++) {
                k_prop16<0><<<pgrid, 256, 0, stream>>>(zcat + (size_t)(k - 1) * ZSL,
                                                       zcat + (size_t)k * ZSL,
                                                       norm, rs, csrc, ew,
                                                       nullptr, nullptr, nullptr);
            }
            k_mm<768, 0, 0, 0, 0, 1, 1><<<MMGRID, 256, 0, stream>>>(
                zcat, Wb, nullptr, nullptr, nullptr, yh, nullptr, part);
            k_bnfin<<<1, 1024, 0, stream>>>(part, bn_g + (size_t)(m * 2 + 0) * HH,
                                            bn_b + (size_t)(m * 2 + 0) * HH, bnsc, bnsh);
        }
        // ---- s=1 tagconv: hop1 gathers bn(yh) on the fly + writes slice0
        {
            const f16* Wb = wc + (size_t)(m * 2 + 1) * 128 * 768;
            k_prop16<1><<<pgrid, 256, 0, stream>>>(yh, zcat + ZSL,
                                                   norm, rs, csrc, ew,
                                                   bnsc, bnsh, zcat);
            for (int k = 2; k <= KK; k++) {
                k_prop16<0><<<pgrid, 256, 0, stream>>>(zcat + (size_t)(k - 1) * ZSL,
                                                       zcat + (size_t)k * ZSL,
                                                       norm, rs, csrc, ew,
                                                       nullptr, nullptr, nullptr);
            }
            k_mm<768, 0, 0, 0, 0, 1, 1><<<MMGRID, 256, 0, stream>>>(
                zcat, Wb, nullptr, nullptr, nullptr, yh, nullptr, part);
            k_bnfin<<<1, 1024, 0, stream>>>(part, bn_g + (size_t)(m * 2 + 1) * HH,
                                            bn_b + (size_t)(m * 2 + 1) * HH, bnsc, bnsh);
        }
        // slice0 = bn(yh_s1) for the FF GEMM
        k_bnapply<<<agrid, 256, 0, stream>>>(yh, bnsc, bnsh, zcat);
        // ff + residual: hin = f16(zcat0)@ff_w + ff_b + hin ; also writes zcat slice0
        k_mm<128, 1, 1, 0, 1, 0, 0><<<MMGRID, 256, 0, stream>>>(
            zcat, wf + (size_t)m * 128 * 128, ff_b + (size_t)m * HH, hin,
            hin, nullptr, zcat, nullptr);
    }

    // pose head: t = relu(h@W1+b1) -> ybuf, then pose = t@W2+b2
    k_mm<128, 1, 0, 1, 0, 0, 0><<<MMGRID, 256, 0, stream>>>(
        zcat, wp, pose_b1, nullptr, ybuf, nullptr, nullptr, nullptr);
    k_pose2<<<NN / 4, 128, 0, stream>>>(ybuf, pose_w2, pose_b2, out);

    // labels head
    k_meanpart<<<256, 256, 0, stream>>>(hin, mpart);
    k_labels<<<1, 128, 0, stream>>>(mpart, lab_w1, lab_b1, lab_w2, lab_b2, out);
}